// Round 9
// baseline (420.688 us; speedup 1.0000x reference)
//
#include <hip/hip_runtime.h>
#include <hip/hip_bf16.h>

typedef float f32x4 __attribute__((ext_vector_type(4)));
typedef short s16x8 __attribute__((ext_vector_type(8)));

#define NB   256
#define NU   512
#define ND0  512
#define ND1  1024
#define WROW (ND0 * ND1)   // elements per u-row of w

// ws layout: f32x4 ws4[bid][mf*2+nf][t]  (512 x 16 x 512 f32x4 = 64 MB)
#define WS_BYTES ((size_t)512 * 16 * 512 * 16)

__device__ __forceinline__ unsigned int f2bf_pk(float a, float b) {
  __hip_bfloat16 ha = __float2bfloat16(a);
  __hip_bfloat16 hb = __float2bfloat16(b);
  unsigned short ua, ub;
  __builtin_memcpy(&ua, &ha, 2);
  __builtin_memcpy(&ub, &hb, 2);
  return (unsigned int)ua | ((unsigned int)ub << 16);
}

// CK-style barrier: enforces LDS ordering but does NOT drain vmcnt.
__device__ __forceinline__ void block_sync_lds() {
  asm volatile("s_waitcnt lgkmcnt(0)" ::: "memory");
  __builtin_amdgcn_s_barrier();
}

// async global->LDS DMA, 16B/lane; dest = wave-uniform base + lane*16.
__device__ __forceinline__ void glds16(const void* g, void* l) {
  __builtin_amdgcn_global_load_lds(
      (const __attribute__((address_space(1))) void*)g,
      (__attribute__((address_space(3))) void*)l, 16, 0, 0);
}

// Seed out[b,u] = bias[u]; atomic-fallback path only.
__global__ __launch_bounds__(256) void init_out(const float* __restrict__ bias,
                                                float* __restrict__ out) {
  int idx = blockIdx.x * 256 + threadIdx.x;
  out[idx] = bias[idx & (NU - 1)];
}

// Reduce kernel (ws path): out[b,u] = bias[u] + sum_ic ws-partial.
__global__ __launch_bounds__(256) void reduce_ws(
    const float* __restrict__ bias, const f32x4* __restrict__ ws4,
    float* __restrict__ out) {
  const int g  = blockIdx.x * 256 + threadIdx.x;   // 128 blocks -> 32768
  const int u  = g & 511;
  const int bh = g >> 9;                           // b>>2, 0..63
  const int wm = bh >> 5, mf = (bh >> 2) & 7, lk = bh & 3;
  const int ntile = u >> 7, wn = (u >> 5) & 3, nf = (u >> 4) & 1, l15 = u & 15;
  const int t  = (wm * 4 + wn) * 64 + lk * 16 + l15;
  const size_t base = (size_t)(mf * 2 + nf) * 512 + t;

  f32x4 s0 = {0, 0, 0, 0}, s1 = {0, 0, 0, 0};
#pragma unroll 8
  for (int ic = 0; ic < 128; ic += 2) {
    s0 += ws4[base + (size_t)((ic + 0) * 4 + ntile) * (16 * 512)];
    s1 += ws4[base + (size_t)((ic + 1) * 4 + ntile) * (16 * 512)];
  }
  f32x4 s = s0 + s1;
  const float bv = bias[u];
  const int b0 = bh * 4;
#pragma unroll
  for (int r = 0; r < 4; ++r)
    out[(size_t)(b0 + r) * NU + u] = s[r] + bv;
}

// out(256x512) = Z(256x524288) @ W^T, Z[b, i*1024+j] = x[b,i]*y[b,j].
// Grid: 512 blocks = 4 u-tiles x 128 K-chunks. Block: 512 thr, 8 waves (2m x 4n).
//
// R9: W path replaced by a DEPTH-2 global_load_lds ring (everything else
// from the proven R3 skeleton: A-synth code/swizzle/y/x pattern and MFMA
// A-addressing verbatim). Rationale: depth-1 register prefetch exposes
// ~4k cy/iter of burst latency and cannot be deepened (VGPR cliff,
// R1/R2/R6); R5's DMA attempt failed on 1-block/CU occupancy + fp32-frag
// fatness at 1024t. Here: BK=32 per iteration (128 iters), W fp32 tile
// 128x32 = 16KB, ring of 3 -> LDS = 32K A + 48K W = 80KB = exactly
// 2 blocks/CU. A-tile still holds j-span 64, consumed over 2 iterations
// (kcol = (it&1)*64). W(t+2) issued at iter t AFTER the y-loads, so each
// y-consume emits a counted vmcnt(2) that drains only DMAs >= 1 full
// iteration old; explicit pre-barrier2 guard vmcnt(4)/(2)/(0) never
// drains the young DMAs (T4 discipline). wv/wvn + the W-pack phase are
// gone (-32 VGPR, ~95 peak). W frags read fp32 from the ring (2-way bank
// alias via chunk-XOR swizzle = free) and cvt to bf16 in-register.
//
// Swizzle (both-sides involution, m173): DMA writes LDS linearly; LDS
// chunk position p of row r holds GLOBAL chunk p^(r&7) by pre-swizzling
// the per-lane source address; frag reads use byte = r*128 + ((c^(r&7))<<4).
__global__ __launch_bounds__(512, 4) void bilinear_kern(
    const float* __restrict__ x, const float* __restrict__ y,
    const float* __restrict__ w, float* __restrict__ out,
    float* __restrict__ ws, int use_ws) {
  __shared__ __align__(16) char Alds[32768];   // 256 rows x 128B (64 bf16)
  __shared__ __align__(16) char Wlds[49152];   // 3 x (128 rows x 128B fp32)

  const int t    = threadIdx.x;
  const int lane = t & 63;
  const int l15  = lane & 15;
  const int lk   = lane >> 4;          // 0..3
  const int wid  = t >> 6;             // 0..7
  const int wm   = wid >> 2;           // 0..1
  const int wn   = wid & 3;            // 0..3

  const int nt    = blockIdx.x & 3;    // u-tile
  const int ic    = blockIdx.x >> 2;   // K-chunk: i0 in [ic*4, ic*4+4)
  const int ucol0 = nt * 128 + wn * 32;

  f32x4 acc[8][2];
#pragma unroll
  for (int mf = 0; mf < 8; ++mf)
#pragma unroll
    for (int nf = 0; nf < 2; ++nf)
#pragma unroll
      for (int r = 0; r < 4; ++r) acc[mf][nf][r] = 0.0f;

  // --- A staging map (verbatim R3): rows ar+32p (p=0..7), floats l15*4..+4 ---
  const int ar   = t >> 4;                        // 0..31
  const int awr  = ar * 128 + ((l15 * 8) ^ ((ar & 7) << 4));
  const float* yb = y + (size_t)ar * ND1 + l15 * 4;

  // --- W DMA map: issue q (0,1) covers rows wid*16 + q*8 + (lane>>3),
  // LDS chunk pos lane&7 must hold global chunk (lane&7)^(row&7); row&7 =
  // lane>>3 for both q, so source float offset = ((lane&7)^(lane>>3))*4 ---
  const int rl = lane >> 3;                       // 0..7
  const int cs = ((lane & 7) ^ rl) * 4;
  const float* wg0 = w + (size_t)(nt * 128 + wid * 16 + rl) * WROW + cs;
  const float* wg1 = w + (size_t)(nt * 128 + wid * 16 + 8 + rl) * WROW + cs;
  char* const wdst = Wlds + wid * 2048;           // + buf*16384 (+1024 q=1)

  const int afswz = (l15 & 7) << 4;

  // ---- prologue: xv for i0; DMA tiles 0 (buf0) and 1 (buf1) ----
  float xv[8];
#pragma unroll
  for (int p = 0; p < 8; ++p)
    xv[p] = x[(size_t)(ar + 32 * p) * ND0 + ic * 4];
  {
    const size_t o0 = (size_t)(ic * 4) * ND1;     // tile 0: i=ic*4, j=0
    glds16(wg0 + o0, wdst);
    glds16(wg1 + o0, wdst + 1024);
    const size_t o1 = o0 + 32;                    // tile 1: j=32
    glds16(wg0 + o1, wdst + 16384);
    glds16(wg1 + o1, wdst + 16384 + 1024);
  }

  int cur = 0;   // ring buffer holding tile `it`
  for (int it = 0; it < 128; ++it) {
    block_sync_lds();   // barrier1: prev phase-2 reads done (A free, ring slot free)

    if ((it & 31) == 0 && it) {   // x column rollover (i changes every 32 iters)
      const int ii = ic * 4 + (it >> 5);
#pragma unroll
      for (int p = 0; p < 8; ++p)
        xv[p] = x[(size_t)(ar + 32 * p) * ND0 + ii];
    }

    const int nb = (cur >= 1) ? (cur - 1) : 2;    // (cur+2)%3
    char* dst = Wlds + nb * 16384 + wid * 2048;

    if ((it & 1) == 0) {
      // ---- A-tile synth (R3 code): j-span 64 for this tile-pair ----
      const int j0 = ((it >> 1) & 15) * 64;
#pragma unroll
      for (int g = 0; g < 2; ++g) {
        f32x4 v[4];
#pragma unroll
        for (int pp = 0; pp < 4; ++pp)
          v[pp] = *(const f32x4*)(yb + (size_t)(g * 4 + pp) * 32 * ND1 + j0);
        if (g == 0 && it < 126) {
          // DMA W(it+2): issued AFTER the g0 y-loads -> the y-consume below
          // emits vmcnt(2), keeping these in flight; drains only DMA(it+1)
          // (>= 1 full iteration old).
          const int tn = it + 2;
          const size_t on = (size_t)(ic * 4 + (tn >> 5)) * ND1
                          + (size_t)((tn & 31) * 32);
          glds16(wg0 + on, dst);
          glds16(wg1 + on, dst + 1024);
        }
#pragma unroll
        for (int pp = 0; pp < 4; ++pp) {
          const int p = g * 4 + pp;
          unsigned long long pk =
              (unsigned long long)f2bf_pk(xv[p] * v[pp][0], xv[p] * v[pp][1]) |
              ((unsigned long long)f2bf_pk(xv[p] * v[pp][2], xv[p] * v[pp][3]) << 32);
          *(unsigned long long*)(Alds + awr + p * 4096) = pk;
        }
      }
    } else {
      if (it < 126) {
        const int tn = it + 2;
        const size_t on = (size_t)(ic * 4 + (tn >> 5)) * ND1
                        + (size_t)((tn & 31) * 32);
        glds16(wg0 + on, dst);
        glds16(wg1 + on, dst + 1024);
      }
    }

    // ---- counted guard: force W(it) landed, keep W(it+1),W(it+2) in flight ----
    if (it < 126)
      asm volatile("s_waitcnt vmcnt(4) lgkmcnt(0)" ::: "memory");
    else if (it == 126)
      asm volatile("s_waitcnt vmcnt(2) lgkmcnt(0)" ::: "memory");
    else
      asm volatile("s_waitcnt vmcnt(0) lgkmcnt(0)" ::: "memory");
    __builtin_amdgcn_s_barrier();   // barrier2: W(it) + A visible block-wide

    // ---- MFMA over BK=32: W frags fp32 -> bf16 in-reg; A slice kc ----
    const char* Wcur = Wlds + cur * 16384;
    const int kc = (it & 1) * 64;
    s16x8 bfr[2];
#pragma unroll
    for (int nf = 0; nf < 2; ++nf) {
      const int row = wn * 32 + nf * 16 + l15;
      const int r7  = row & 7;
      const char* base = Wcur + row * 128;
      const int c0 = lk * 2;
      f32x4 wlo = *(const f32x4*)(base + ((c0 ^ r7) << 4));
      f32x4 whi = *(const f32x4*)(base + (((c0 + 1) ^ r7) << 4));
      unsigned int pk[4] = { f2bf_pk(wlo[0], wlo[1]), f2bf_pk(wlo[2], wlo[3]),
                             f2bf_pk(whi[0], whi[1]), f2bf_pk(whi[2], whi[3]) };
      __builtin_memcpy(&bfr[nf], pk, 16);
    }
#pragma unroll
    for (int mf = 0; mf < 8; ++mf) {
      const int row = wm * 128 + mf * 16 + l15;
      s16x8 af = *(const s16x8*)(Alds + row * 128 + ((kc + lk * 16) ^ afswz));
      acc[mf][0] = __builtin_amdgcn_mfma_f32_16x16x32_bf16(af, bfr[0], acc[mf][0], 0, 0, 0);
      acc[mf][1] = __builtin_amdgcn_mfma_f32_16x16x32_bf16(af, bfr[1], acc[mf][1], 0, 0, 0);
    }

    cur = (cur == 2) ? 0 : cur + 1;
  }

  // ---- epilogue (R8) ----
  if (use_ws) {
    f32x4* ws4 = (f32x4*)ws + (size_t)blockIdx.x * (16 * 512) + t;
#pragma unroll
    for (int mf = 0; mf < 8; ++mf)
#pragma unroll
      for (int nf = 0; nf < 2; ++nf)
        __builtin_nontemporal_store(acc[mf][nf], ws4 + (mf * 2 + nf) * 512);
  } else {
#pragma unroll
    for (int mf = 0; mf < 8; ++mf) {
      const int grow = wm * 128 + mf * 16 + lk * 4;
#pragma unroll
      for (int nf = 0; nf < 2; ++nf) {
        const int gcol = ucol0 + nf * 16 + l15;
#pragma unroll
        for (int r = 0; r < 4; ++r) {
          atomicAdd(out + (size_t)(grow + r) * NU + gcol, acc[mf][nf][r]);
        }
      }
    }
  }
}

extern "C" void kernel_launch(void* const* d_in, const int* in_sizes, int n_in,
                              void* d_out, int out_size, void* d_ws, size_t ws_size,
                              hipStream_t stream) {
  const float* x    = (const float*)d_in[0];
  const float* y    = (const float*)d_in[1];
  const float* w    = (const float*)d_in[2];
  const float* bias = (const float*)d_in[3];
  float* out = (float*)d_out;

  const bool use_ws = (d_ws != nullptr) && (ws_size >= WS_BYTES);
  if (use_ws) {
    bilinear_kern<<<512, 512, 0, stream>>>(x, y, w, out, (float*)d_ws, 1);
    reduce_ws<<<128, 256, 0, stream>>>(bias, (const f32x4*)d_ws, out);
  } else {
    init_out<<<512, 256, 0, stream>>>(bias, out);
    bilinear_kern<<<512, 512, 0, stream>>>(x, y, w, out, nullptr, 0);
  }
}

// Round 10
// 294.719 us; speedup vs baseline: 1.4274x; 1.4274x over previous
//
#include <hip/hip_runtime.h>
#include <hip/hip_bf16.h>

typedef float f32x4 __attribute__((ext_vector_type(4)));
typedef short s16x8 __attribute__((ext_vector_type(8)));

#define NB   256
#define NU   512
#define ND0  512
#define ND1  1024
#define WROW (ND0 * ND1)   // elements per u-row of w

// ws layout: f32x4 ws4[bid][mf*2+nf][t]  (512 x 16 x 512 f32x4 = 64 MB)
#define WS_BYTES ((size_t)512 * 16 * 512 * 16)

__device__ __forceinline__ unsigned int f2bf_pk(float a, float b) {
  __hip_bfloat16 ha = __float2bfloat16(a);
  __hip_bfloat16 hb = __float2bfloat16(b);
  unsigned short ua, ub;
  __builtin_memcpy(&ua, &ha, 2);
  __builtin_memcpy(&ub, &hb, 2);
  return (unsigned int)ua | ((unsigned int)ub << 16);
}

// CK-style barrier: enforces LDS ordering but does NOT drain vmcnt,
// so register-prefetch global loads stay in flight across it.
__device__ __forceinline__ void block_sync_lds() {
  asm volatile("s_waitcnt lgkmcnt(0)" ::: "memory");
  __builtin_amdgcn_s_barrier();
}

// Seed out[b,u] = bias[u]; atomic-fallback path only.
__global__ __launch_bounds__(256) void init_out(const float* __restrict__ bias,
                                                float* __restrict__ out) {
  int idx = blockIdx.x * 256 + threadIdx.x;
  out[idx] = bias[idx & (NU - 1)];
}

// Reduce kernel (ws path): out[b,u] = bias[u] + sum_ic ws-partial.
__global__ __launch_bounds__(256) void reduce_ws(
    const float* __restrict__ bias, const f32x4* __restrict__ ws4,
    float* __restrict__ out) {
  const int g  = blockIdx.x * 256 + threadIdx.x;   // 128 blocks -> 32768
  const int u  = g & 511;
  const int bh = g >> 9;                           // b>>2, 0..63
  const int wm = bh >> 5, mf = (bh >> 2) & 7, lk = bh & 3;
  const int ntile = u >> 7, wn = (u >> 5) & 3, nf = (u >> 4) & 1, l15 = u & 15;
  const int t  = (wm * 4 + wn) * 64 + lk * 16 + l15;
  const size_t base = (size_t)(mf * 2 + nf) * 512 + t;

  f32x4 s0 = {0, 0, 0, 0}, s1 = {0, 0, 0, 0};
#pragma unroll 8
  for (int ic = 0; ic < 128; ic += 2) {
    s0 += ws4[base + (size_t)((ic + 0) * 4 + ntile) * (16 * 512)];
    s1 += ws4[base + (size_t)((ic + 1) * 4 + ntile) * (16 * 512)];
  }
  f32x4 s = s0 + s1;
  const float bv = bias[u];
  const int b0 = bh * 4;
#pragma unroll
  for (int r = 0; r < 4; ++r)
    out[(size_t)(b0 + r) * NU + u] = s[r] + bv;
}

// out(256x512) = Z(256x524288) @ W^T, Z[b, i*1024+j] = x[b,i]*y[b,j].
// Grid: 512 blocks = 4 u-tiles x 128 K-chunks. Block: 512 thr, 8 waves (2m x 4n).
//
// R10 = R8 (291.8us best) with ONE fenced relocation, derived from the
// vmem-FIFO law (a wait for load L drains everything older than L):
//  - y-loads are consumed in-iteration, so any W load issued BEFORE them
//    is drained by the y-consume's vmcnt(0) (this is exactly why R6's
//    wvn-at-top regressed to 332us, and R4 to 455us).
//  - In R8 wvn is issued after pack: in-flight span to the bottom copy is
//    only barrier2+MFMA (~600cy); stall at copy ~ loaded-latency - 600.
//  - The pack does NOT wait (wv register-resident since last copy's
//    drain), so the wvn issue moves to AFTER A-synth / BEFORE pack:
//    still younger than all y-loads (no early drain), span grows by the
//    pack duration, liveness unchanged (wv dies at pack; no renaming).
//  sched_barrier(0) fences pin [synth] | [wvn+xv issue] | [pack] so the
//  compiler can't hoist wvn above the y-loads (R6 failure mode) or sink
//  it back after pack (R8 status quo). Everything else is R8 verbatim.
__global__ __launch_bounds__(512, 4) void bilinear_kern(
    const float* __restrict__ x, const float* __restrict__ y,
    const float* __restrict__ w, float* __restrict__ out,
    float* __restrict__ ws, int use_ws) {
  __shared__ char Alds[32768];   // 256 rows x 128B (64 bf16), XOR-swizzled
  __shared__ char Wlds[16384];   // 128 rows x 128B (64 bf16), XOR-swizzled

  const int t    = threadIdx.x;
  const int lane = t & 63;
  const int l15  = lane & 15;
  const int lk   = lane >> 4;          // 0..3
  const int wid  = t >> 6;             // 0..7
  const int wm   = wid >> 2;           // 0..1  (m-group: rows wm*128)
  const int wn   = wid & 3;            // 0..3  (n-group: cols wn*32)

  const int nt    = blockIdx.x & 3;    // u-tile
  const int ic    = blockIdx.x >> 2;   // K-chunk: i0 in [ic*4, ic*4+4)
  const int off   = (nt << 4) | (ic & 15);   // start phase, 0..63 (R7 stagger)
  const int ucol0 = nt * 128 + wn * 32;

  f32x4 acc[8][2];
#pragma unroll
  for (int mf = 0; mf < 8; ++mf)
#pragma unroll
    for (int nf = 0; nf < 2; ++nf)
#pragma unroll
      for (int r = 0; r < 4; ++r) acc[mf][nf][r] = 0.0f;

  // --- A staging map: thread covers rows ar+32p (p=0..7), floats l15*4..+4 ---
  const int ar   = t >> 4;                        // 0..31
  const int aswz = (ar & 7) << 4;                 // (row&7) invariant under +32p
  const int awr  = ar * 128 + ((l15 * 8) ^ aswz); // +p*4096
  const float* yb = y + (size_t)ar * ND1 + l15 * 4;

  // --- W staging map: thread covers rows wrb+4q (q=0..3), floats l15*4..+4 ---
  const int wrb = wid * 16 + lk;                  // 0..127 (wid*16+lk<128)
  const float* wq = w + (size_t)(nt * 128 + wrb) * WROW + l15 * 4;

  // frag-read swizzle: frag rows are l15 mod 8 in both tiles
  const int afswz = (l15 & 7) << 4;

  // ---- prologue: prefetch step-0's W and its x column (staggered phase) ----
  f32x4 wv[4], wvn[4];
  const int ii0 = ic * 4 + (off >> 4);
  {
    const float* p0 = wq + (size_t)ii0 * ND1 + (off & 15) * 64;
#pragma unroll
    for (int q = 0; q < 4; ++q)
      wv[q] = __builtin_nontemporal_load((const f32x4*)(p0 + (size_t)q * 4 * WROW));
  }
  float xv[8];
#pragma unroll
  for (int p = 0; p < 8; ++p)
    xv[p] = x[(size_t)(ar + 32 * p) * ND0 + ii0];

  for (int it = 0; it < 64; ++it) {
    const int s  = (it + off) & 63;    // staggered sweep position
    const int j0 = (s & 15) * 64;

    block_sync_lds();   // barrier1: previous tiles fully consumed

    // ---- A-tile synth: SY[b,jj] = bf16(x[b,i0]*y[b,j0+jj]) ----
    // (y issue+consume within this phase; nothing older outstanding)
#pragma unroll
    for (int g = 0; g < 2; ++g) {
      f32x4 v[4];
#pragma unroll
      for (int pp = 0; pp < 4; ++pp)
        v[pp] = *(const f32x4*)(yb + (size_t)(g * 4 + pp) * 32 * ND1 + j0);
#pragma unroll
      for (int pp = 0; pp < 4; ++pp) {
        const int p = g * 4 + pp;
        unsigned long long pk =
            (unsigned long long)f2bf_pk(xv[p] * v[pp][0], xv[p] * v[pp][1]) |
            ((unsigned long long)f2bf_pk(xv[p] * v[pp][2], xv[p] * v[pp][3]) << 32);
        *(unsigned long long*)(Alds + awr + p * 4096) = pk;
      }
    }

    __builtin_amdgcn_sched_barrier(0);   // fence: wvn must not hoist above y

    // ---- prefetch next step, issued BEFORE pack (R10 move): younger than
    // all y-loads (no early drain), in flight through pack+barrier2+MFMA ----
    if (it < 63) {
      const int sn = (s + 1) & 63;
      const int ii = ic * 4 + (sn >> 4);
      const int jn = (sn & 15) * 64;
      const float* pn = wq + (size_t)ii * ND1 + jn;
#pragma unroll
      for (int q = 0; q < 4; ++q)
        wvn[q] = __builtin_nontemporal_load((const f32x4*)(pn + (size_t)q * 4 * WROW));
      if ((s & 15) == 15) {
#pragma unroll
        for (int pp = 0; pp < 8; ++pp)
          xv[pp] = x[(size_t)(ar + 32 * pp) * ND0 + ii];
      }
    }

    __builtin_amdgcn_sched_barrier(0);   // fence: pack must not hoist above wvn

    // ---- W-tile pack: wv (register-resident since last copy) -> LDS;
    // NO vmem wait here ----
#pragma unroll
    for (int q = 0; q < 4; ++q) {
      const int row  = wrb + 4 * q;
      const int byte = row * 128 + ((l15 * 8) ^ ((row & 7) << 4));
      unsigned long long pk =
          (unsigned long long)f2bf_pk(wv[q][0], wv[q][1]) |
          ((unsigned long long)f2bf_pk(wv[q][2], wv[q][3]) << 32);
      *(unsigned long long*)(Wlds + byte) = pk;
    }

    block_sync_lds();   // barrier2: tiles visible (lgkmcnt only)

    // ---- MFMA over BK=64 (two k-steps of 32) ----
#pragma unroll
    for (int ks = 0; ks < 2; ++ks) {
      const int kcol = ks * 64;
      s16x8 bf[2];
#pragma unroll
      for (int nf = 0; nf < 2; ++nf) {
        const int row = wn * 32 + nf * 16 + l15;
        bf[nf] = *(const s16x8*)(Wlds + row * 128 + ((kcol + lk * 16) ^ afswz));
      }
#pragma unroll
      for (int mf = 0; mf < 8; ++mf) {
        const int row = wm * 128 + mf * 16 + l15;
        s16x8 af = *(const s16x8*)(Alds + row * 128 + ((kcol + lk * 16) ^ afswz));
        acc[mf][0] = __builtin_amdgcn_mfma_f32_16x16x32_bf16(af, bf[0], acc[mf][0], 0, 0, 0);
        acc[mf][1] = __builtin_amdgcn_mfma_f32_16x16x32_bf16(af, bf[1], acc[mf][1], 0, 0, 0);
      }
    }

    // ---- copy: waits on wvn (in flight since before pack: span ~doubled) ----
#pragma unroll
    for (int q = 0; q < 4; ++q) wv[q] = wvn[q];
  }

  // ---- epilogue (R8) ----
  if (use_ws) {
    f32x4* ws4 = (f32x4*)ws + (size_t)blockIdx.x * (16 * 512) + t;
#pragma unroll
    for (int mf = 0; mf < 8; ++mf)
#pragma unroll
      for (int nf = 0; nf < 2; ++nf)
        __builtin_nontemporal_store(acc[mf][nf], ws4 + (mf * 2 + nf) * 512);
  } else {
#pragma unroll
    for (int mf = 0; mf < 8; ++mf) {
      const int grow = wm * 128 + mf * 16 + lk * 4;
#pragma unroll
      for (int nf = 0; nf < 2; ++nf) {
        const int gcol = ucol0 + nf * 16 + l15;
#pragma unroll
        for (int r = 0; r < 4; ++r) {
          atomicAdd(out + (size_t)(grow + r) * NU + gcol, acc[mf][nf][r]);
        }
      }
    }
  }
}

extern "C" void kernel_launch(void* const* d_in, const int* in_sizes, int n_in,
                              void* d_out, int out_size, void* d_ws, size_t ws_size,
                              hipStream_t stream) {
  const float* x    = (const float*)d_in[0];
  const float* y    = (const float*)d_in[1];
  const float* w    = (const float*)d_in[2];
  const float* bias = (const float*)d_in[3];
  float* out = (float*)d_out;

  const bool use_ws = (d_ws != nullptr) && (ws_size >= WS_BYTES);
  if (use_ws) {
    bilinear_kern<<<512, 512, 0, stream>>>(x, y, w, out, (float*)d_ws, 1);
    reduce_ws<<<128, 256, 0, stream>>>(bias, (const f32x4*)d_ws, out);
  } else {
    init_out<<<512, 256, 0, stream>>>(bias, out);
    bilinear_kern<<<512, 512, 0, stream>>>(x, y, w, out, nullptr, 0);
  }
}